// Round 7
// baseline (201.441 us; speedup 1.0000x reference)
//
#include <hip/hip_runtime.h>
#include <cstdint>
#include <cstddef>

// Problem shape (fixed by the reference setup_inputs)
#define MDIM 8192
#define KDIM 2048
#define NDIM 2048
#define QBLK 128
#define KB   (KDIM / QBLK)   // 16
#define NB   (NDIM / QBLK)   // 16

typedef float floatx4 __attribute__((ext_vector_type(4)));
typedef int   int4v   __attribute__((ext_vector_type(4)));
typedef int   int8v   __attribute__((ext_vector_type(8)));

#define AS1 __attribute__((address_space(1)))
#define AS3 __attribute__((address_space(3)))

// ---------------------------------------------------------------------------
// fp8 e4m3fn helpers (software, bit-exact) — prep weight path
// ---------------------------------------------------------------------------
__device__ inline unsigned e4m3_encode(float r) {  // r exactly on fp8 grid
    unsigned u = __float_as_uint(r);
    unsigned s = (u >> 24) & 0x80u;
    float a = fabsf(r);
    if (a < 0.015625f) return s | (unsigned)(a * 512.0f + 0.25f);
    unsigned e = ((u >> 23) & 0xFFu) - 120u;       // 1..15
    unsigned m = (u >> 20) & 7u;
    return s | (e << 3) | m;
}

__device__ inline int is_expbyte(unsigned b) {   // plausible f32/bf16 hi byte for fp8-exact value
    unsigned e = b & 0x7Fu;
    return (e >= 0x3Bu && e <= 0x43u) || e == 0x00u;
}

// ---------------------------------------------------------------------------
// Workspace layout
//   xq  [M][K]  fp8 bytes            @ 0        (16 MB)
//   wq8 [N][K]  fp8 bytes            @ 16 MB    (4 MB)
//   xs  [M][KB] f32 act scales       @ 20 MB    (512 KB)
// ---------------------------------------------------------------------------
#define XQ_OFF  0
#define WQ_OFF  ((size_t)MDIM * KDIM)
#define XS_OFF  (WQ_OFF + (size_t)NDIM * KDIM)

#define QXB ((MDIM * KB) / 16)         // 8192 act-quant blocks (16 qblocks each)
#define DWB ((NDIM * KDIM / 8) / 256)  // 2048 weight blocks

// ---------------------------------------------------------------------------
// Prep (unchanged from round 6): act quant (8 elems/lane, 16 lanes per
// (1,128) block) -> fp8 bytes + scales via HW v_cvt_pk_fp8_f32 (bit-identical
// RNE from exact IEEE division); weight -> fp8 bytes (delivery format
// classified per wave via ballot).
// ---------------------------------------------------------------------------
__global__ __launch_bounds__(256) void prep_kernel(const float* __restrict__ x,
                                                   const void* __restrict__ wq,
                                                   unsigned char* __restrict__ xq,
                                                   unsigned char* __restrict__ wq8,
                                                   float* __restrict__ xs) {
    const int tid = threadIdx.x;

    if (blockIdx.x < QXB) {
        // ---- activation quant: one 16-lane group per (1,128) block ----
        const int g = tid >> 4;
        const int l = tid & 15;
        const size_t bi = (size_t)blockIdx.x * 16 + g;   // = m*KB + kb
        const size_t base = bi << 7;

        const float4* xp = (const float4*)(x + base + (size_t)l * 8);
        const float4 v0 = xp[0], v1 = xp[1];
        float a = fmaxf(fmaxf(fmaxf(fabsf(v0.x), fabsf(v0.y)), fmaxf(fabsf(v0.z), fabsf(v0.w))),
                        fmaxf(fmaxf(fabsf(v1.x), fabsf(v1.y)), fmaxf(fabsf(v1.z), fabsf(v1.w))));
        a = fmaxf(a, __shfl_xor(a, 1));
        a = fmaxf(a, __shfl_xor(a, 2));
        a = fmaxf(a, __shfl_xor(a, 4));
        a = fmaxf(a, __shfl_xor(a, 8));

        const float scale = fmaxf(a, 1e-12f) / 448.0f;
        if (l == 0) xs[bi] = scale;

        // exact IEEE divisions (same as reference), HW RNE pack to fp8
        const float q0 = v0.x / scale, q1 = v0.y / scale, q2 = v0.z / scale, q3 = v0.w / scale;
        const float q4 = v1.x / scale, q5 = v1.y / scale, q6 = v1.z / scale, q7 = v1.w / scale;
        int w0 = __builtin_amdgcn_cvt_pk_fp8_f32(q0, q1, 0, false);
        w0 = __builtin_amdgcn_cvt_pk_fp8_f32(q2, q3, w0, true);
        int w1 = __builtin_amdgcn_cvt_pk_fp8_f32(q4, q5, 0, false);
        w1 = __builtin_amdgcn_cvt_pk_fp8_f32(q6, q7, w1, true);
        *(uint2*)(xq + base + (size_t)l * 8) = make_uint2((unsigned)w0, (unsigned)w1);
    } else {
        // ---- weight repack to fp8 bytes ----
        const int lane = tid & 63;
        const unsigned pw = ((const unsigned*)wq)[lane];
        const unsigned long long m3 = __ballot(is_expbyte((pw >> 24) & 0xFFu));
        const unsigned long long m1 = __ballot(((pw >> 8) & 0xFFu) == 0u);
        const int f = (__popcll(m3) >= 56) ? ((__popcll(m1) >= 56) ? 2 : 1) : 0;

        const size_t idx = (size_t)(blockIdx.x - QXB) * 256 + tid;
        const size_t off = idx * 8;

        unsigned lo, hi;
        if (f == 2) {              // float32 upcast delivery (values exactly on fp8 grid)
            const float4* p = (const float4*)((const float*)wq + off);
            const float4 a = p[0], b = p[1];
            lo = e4m3_encode(a.x) | (e4m3_encode(a.y) << 8) | (e4m3_encode(a.z) << 16) | (e4m3_encode(a.w) << 24);
            hi = e4m3_encode(b.x) | (e4m3_encode(b.y) << 8) | (e4m3_encode(b.z) << 16) | (e4m3_encode(b.w) << 24);
        } else if (f == 1) {       // bf16 upcast delivery
            const ushort4 h0 = *(const ushort4*)((const unsigned short*)wq + off);
            const ushort4 h1 = *(((const ushort4*)((const unsigned short*)wq + off)) + 1);
            lo = e4m3_encode(__uint_as_float((unsigned)h0.x << 16))
               | (e4m3_encode(__uint_as_float((unsigned)h0.y << 16)) << 8)
               | (e4m3_encode(__uint_as_float((unsigned)h0.z << 16)) << 16)
               | (e4m3_encode(__uint_as_float((unsigned)h0.w << 16)) << 24);
            hi = e4m3_encode(__uint_as_float((unsigned)h1.x << 16))
               | (e4m3_encode(__uint_as_float((unsigned)h1.y << 16)) << 8)
               | (e4m3_encode(__uint_as_float((unsigned)h1.z << 16)) << 16)
               | (e4m3_encode(__uint_as_float((unsigned)h1.w << 16)) << 24);
        } else {                   // already raw fp8 bytes
            const uint2 d = *(const uint2*)((const unsigned char*)wq + off);
            lo = d.x; hi = d.y;
        }
        *(uint2*)(wq8 + off) = make_uint2(lo, hi);
    }
}

// ---------------------------------------------------------------------------
// Primary GEMM: 128x128 tile, 4 waves (2x2 of 64x64), MX fp8 K=128 per MFMA,
// XOR-swizzled 16B chunks.  Round-6 body (128-total-reg occupancy shape:
// bf[4] held, af rolling, premultiplied sxs) with two deltas:
//   1. SPLIT-STAGE loop: read bf(sB) -> __syncthreads (frees sB, drains A(t))
//      -> STAGE_B(t+1) -> MFMA phase reading sA -> __syncthreads (frees sA,
//      drains B(t+1)) -> STAGE_A(t+1).  Each stage's latency now sits under
//      a compute phase (B under ~600cy of MFMA, A under the bf-read phase)
//      instead of under an empty issue->drain gap.  Race-free by
//      construction: __syncthreads = vmcnt(0)+lgkmcnt(0)+barrier, and every
//      stage targets a region all waves finished reading before the
//      preceding __syncthreads.  Same 2 barriers/tile as round 6.
//   2. XCD-grouped bijective tile map (1024 blocks, nwg%8==0): XCD g gets
//      m-tiles [8g,8g+8) x all 16 n-tiles -> A/B panels L2-resident per XCD
//      (R1 measured FETCH 73->25 MB with this family of maps).
// Spill tripwire: WRITE_SIZE must stay ~65-71e3 KB.
// ---------------------------------------------------------------------------
__global__ __launch_bounds__(256, 4) void gemm_mx_kernel(const unsigned char* __restrict__ Aq,
                                                         const unsigned char* __restrict__ Bq,
                                                         const float* __restrict__ xs,
                                                         const float* __restrict__ wsc,
                                                         float* __restrict__ C) {
    __shared__ unsigned char sA[128 * 128];   // 16 KB
    __shared__ unsigned char sB[128 * 128];   // 16 KB
    __shared__ float sxs[KB][128];            // 8 KB combined scales xs*wsk

    const int tid  = threadIdx.x;
    const int wave = tid >> 6;
    const int lane = tid & 63;
    const int lrow = lane & 15;
    const int lk   = lane >> 4;          // k-group (32 bytes each)
    const int lk4  = lk * 4;
    const int wm   = (wave & 1) * 64;
    const int wn   = (wave >> 1) * 64;

    // XCD-grouped bijective tile map: 1024 blocks (64 m-tiles x 16 n-tiles);
    // XCD g (bid&7==g) owns lid in [g*128,(g+1)*128) = m-tiles [8g,8g+8).
    const int bid = blockIdx.x;
    const int lid = ((bid & 7) << 7) | (bid >> 3);
    const int m0  = (lid >> 4) * 128;
    const int n0  = (lid & 15) * 128;
    const int nb  = n0 >> 7;

    // staging: thread t -> LDS bytes [t*16 + it*4096): row = t/8 + it*32,
    // physical chunk = t&7 holding logical chunk (t&7)^(row&7).
    const int srow = tid >> 3;
    const int gck  = (tid & 7) ^ (srow & 7);
    const unsigned char* agp = Aq + (size_t)(m0 + srow) * KDIM + gck * 16;
    const unsigned char* bgp = Bq + (size_t)(n0 + srow) * KDIM + gck * 16;

#define STAGE_A(kb_) do {                                                             \
    const size_t koff_ = (size_t)(kb_) * QBLK;                                        \
    _Pragma("unroll")                                                                 \
    for (int it = 0; it < 4; ++it)                                                    \
        __builtin_amdgcn_global_load_lds(                                             \
            (const AS1 void*)(agp + (size_t)(it * 32) * KDIM + koff_),                \
            (AS3 void*)(sA + tid * 16 + it * 4096), 16, 0, 0);                        \
} while (0)
#define STAGE_B(kb_) do {                                                             \
    const size_t koff_ = (size_t)(kb_) * QBLK;                                        \
    _Pragma("unroll")                                                                 \
    for (int it = 0; it < 4; ++it)                                                    \
        __builtin_amdgcn_global_load_lds(                                             \
            (const AS1 void*)(bgp + (size_t)(it * 32) * KDIM + koff_),                \
            (AS3 void*)(sB + tid * 16 + it * 4096), 16, 0, 0);                        \
} while (0)

    // prologue: tile-0 stages + combined-scale staging, full drain once
    STAGE_B(0);
    STAGE_A(0);
    if (tid < 128) {
        const float4* xp = (const float4*)(xs + (size_t)(m0 + tid) * KB);
        const float* wp = wsc + nb * KB;
#pragma unroll
        for (int q = 0; q < 4; ++q) {
            const float4 v = xp[q];
            sxs[q * 4 + 0][tid] = v.x * wp[q * 4 + 0];
            sxs[q * 4 + 1][tid] = v.y * wp[q * 4 + 1];
            sxs[q * 4 + 2][tid] = v.z * wp[q * 4 + 2];
            sxs[q * 4 + 3][tid] = v.w * wp[q * 4 + 3];
        }
    }
    __syncthreads();   // tile 0 + scales landed everywhere

    floatx4 acc[4][4] = {};
    const floatx4 zero = {0.f, 0.f, 0.f, 0.f};

    for (int kb = 0; kb < KB; ++kb) {            // 16 iterations, 128 K each
        // ---- phase 1: B fragments (sB fully consumed here) ----
        int8v bf[4];
#pragma unroll
        for (int j = 0; j < 4; ++j) {
            const int Rb = wn + j * 16 + lrow;
            const int d0 = (lk * 2) ^ (Rb & 7);
            const int d1 = (lk * 2 + 1) ^ (Rb & 7);
            int4v blo = *(const int4v*)(sB + Rb * 128 + d0 * 16);
            int4v bhi = *(const int4v*)(sB + Rb * 128 + d1 * 16);
            bf[j] = __builtin_shufflevector(blo, bhi, 0, 1, 2, 3, 4, 5, 6, 7);
        }

        __syncthreads();                 // sB free; A(kb) drained everywhere
        if (kb + 1 < KB) STAGE_B(kb + 1);   // lands during the MFMA phase

        // ---- phase 2: per-i A fragment + MFMA (sA fully consumed here) ----
#pragma unroll
        for (int i = 0; i < 4; ++i) {
            const int Ra = wm + i * 16 + lrow;
            const int c0 = (lk * 2) ^ (Ra & 7);
            const int c1 = (lk * 2 + 1) ^ (Ra & 7);
            int4v alo = *(const int4v*)(sA + Ra * 128 + c0 * 16);
            int4v ahi = *(const int4v*)(sA + Ra * 128 + c1 * 16);
            int8v af = __builtin_shufflevector(alo, ahi, 0, 1, 2, 3, 4, 5, 6, 7);

            // combined per-row scales for this k-block (C/D row = lk*4 + r)
            const floatx4 cs = *(const floatx4*)&sxs[kb][wm + i * 16 + lk4];

#pragma unroll
            for (int j = 0; j < 4; ++j) {
                floatx4 blk = __builtin_amdgcn_mfma_scale_f32_16x16x128_f8f6f4(
                    af, bf[j], zero, 0, 0, 0, 0x7F7F7F7F, 0, 0x7F7F7F7F);
#pragma unroll
                for (int r = 0; r < 4; ++r)
                    acc[i][j][r] += cs[r] * blk[r];
            }
        }

        __syncthreads();                 // sA free; B(kb+1) drained everywhere
        if (kb + 1 < KB) STAGE_A(kb + 1);   // lands during next bf-read phase
    }
#undef STAGE_A
#undef STAGE_B

    // Epilogue: col = lane&15, row = lk*4 + r.
#pragma unroll
    for (int i = 0; i < 4; ++i) {
        const int row0 = m0 + wm + i * 16 + lk4;
#pragma unroll
        for (int r = 0; r < 4; ++r) {
            float* cp = C + (size_t)(row0 + r) * NDIM + n0 + wn + lrow;
#pragma unroll
            for (int j = 0; j < 4; ++j)
                cp[j * 16] = acc[i][j][r];
        }
    }
}

// ---------------------------------------------------------------------------
extern "C" void kernel_launch(void* const* d_in, const int* in_sizes, int n_in,
                              void* d_out, int out_size, void* d_ws, size_t ws_size,
                              hipStream_t stream) {
    const float* x      = (const float*)d_in[0];
    const void* wq      = d_in[1];
    const float* wscale = (const float*)d_in[2];
    float* y            = (float*)d_out;

    unsigned char* xq  = (unsigned char*)d_ws + XQ_OFF;
    unsigned char* wq8 = (unsigned char*)d_ws + WQ_OFF;
    float* xs          = (float*)((unsigned char*)d_ws + XS_OFF);

    prep_kernel<<<QXB + DWB, 256, 0, stream>>>(x, wq, xq, wq8, xs);
    gemm_mx_kernel<<<(MDIM / 128) * (NDIM / 128), 256, 0, stream>>>(xq, wq8, xs, wscale, y);
}

// Round 8
// 165.758 us; speedup vs baseline: 1.2153x; 1.2153x over previous
//
#include <hip/hip_runtime.h>
#include <cstdint>
#include <cstddef>

// Problem shape (fixed by the reference setup_inputs)
#define MDIM 8192
#define KDIM 2048
#define NDIM 2048
#define QBLK 128
#define KB   (KDIM / QBLK)   // 16
#define NB   (NDIM / QBLK)   // 16

typedef float floatx4 __attribute__((ext_vector_type(4)));
typedef int   int4v   __attribute__((ext_vector_type(4)));
typedef int   int8v   __attribute__((ext_vector_type(8)));

#define AS1 __attribute__((address_space(1)))
#define AS3 __attribute__((address_space(3)))

// ---------------------------------------------------------------------------
// fp8 e4m3fn helpers (software, bit-exact) — prep weight path
// ---------------------------------------------------------------------------
__device__ inline unsigned e4m3_encode(float r) {  // r exactly on fp8 grid
    unsigned u = __float_as_uint(r);
    unsigned s = (u >> 24) & 0x80u;
    float a = fabsf(r);
    if (a < 0.015625f) return s | (unsigned)(a * 512.0f + 0.25f);
    unsigned e = ((u >> 23) & 0xFFu) - 120u;       // 1..15
    unsigned m = (u >> 20) & 7u;
    return s | (e << 3) | m;
}

__device__ inline int is_expbyte(unsigned b) {   // plausible f32/bf16 hi byte for fp8-exact value
    unsigned e = b & 0x7Fu;
    return (e >= 0x3Bu && e <= 0x43u) || e == 0x00u;
}

// ---------------------------------------------------------------------------
// Workspace layout
//   xq  [M][K]  fp8 bytes            @ 0        (16 MB)
//   wq8 [N][K]  fp8 bytes            @ 16 MB    (4 MB)
//   xs  [M][KB] f32 act scales       @ 20 MB    (512 KB)
// ---------------------------------------------------------------------------
#define XQ_OFF  0
#define WQ_OFF  ((size_t)MDIM * KDIM)
#define XS_OFF  (WQ_OFF + (size_t)NDIM * KDIM)

#define QXB ((MDIM * KB) / 16)         // 8192 act-quant blocks (16 qblocks each)
#define DWB ((NDIM * KDIM / 8) / 256)  // 2048 weight blocks

// ---------------------------------------------------------------------------
// Prep (unchanged from round 6): act quant (8 elems/lane, 16 lanes per
// (1,128) block) -> fp8 bytes + scales via HW v_cvt_pk_fp8_f32 (bit-identical
// RNE from exact IEEE division); weight -> fp8 bytes (delivery format
// classified per wave via ballot).
// ---------------------------------------------------------------------------
__global__ __launch_bounds__(256) void prep_kernel(const float* __restrict__ x,
                                                   const void* __restrict__ wq,
                                                   unsigned char* __restrict__ xq,
                                                   unsigned char* __restrict__ wq8,
                                                   float* __restrict__ xs) {
    const int tid = threadIdx.x;

    if (blockIdx.x < QXB) {
        // ---- activation quant: one 16-lane group per (1,128) block ----
        const int g = tid >> 4;
        const int l = tid & 15;
        const size_t bi = (size_t)blockIdx.x * 16 + g;   // = m*KB + kb
        const size_t base = bi << 7;

        const float4* xp = (const float4*)(x + base + (size_t)l * 8);
        const float4 v0 = xp[0], v1 = xp[1];
        float a = fmaxf(fmaxf(fmaxf(fabsf(v0.x), fabsf(v0.y)), fmaxf(fabsf(v0.z), fabsf(v0.w))),
                        fmaxf(fmaxf(fabsf(v1.x), fabsf(v1.y)), fmaxf(fabsf(v1.z), fabsf(v1.w))));
        a = fmaxf(a, __shfl_xor(a, 1));
        a = fmaxf(a, __shfl_xor(a, 2));
        a = fmaxf(a, __shfl_xor(a, 4));
        a = fmaxf(a, __shfl_xor(a, 8));

        const float scale = fmaxf(a, 1e-12f) / 448.0f;
        if (l == 0) xs[bi] = scale;

        // exact IEEE divisions (same as reference), HW RNE pack to fp8
        const float q0 = v0.x / scale, q1 = v0.y / scale, q2 = v0.z / scale, q3 = v0.w / scale;
        const float q4 = v1.x / scale, q5 = v1.y / scale, q6 = v1.z / scale, q7 = v1.w / scale;
        int w0 = __builtin_amdgcn_cvt_pk_fp8_f32(q0, q1, 0, false);
        w0 = __builtin_amdgcn_cvt_pk_fp8_f32(q2, q3, w0, true);
        int w1 = __builtin_amdgcn_cvt_pk_fp8_f32(q4, q5, 0, false);
        w1 = __builtin_amdgcn_cvt_pk_fp8_f32(q6, q7, w1, true);
        *(uint2*)(xq + base + (size_t)l * 8) = make_uint2((unsigned)w0, (unsigned)w1);
    } else {
        // ---- weight repack to fp8 bytes ----
        const int lane = tid & 63;
        const unsigned pw = ((const unsigned*)wq)[lane];
        const unsigned long long m3 = __ballot(is_expbyte((pw >> 24) & 0xFFu));
        const unsigned long long m1 = __ballot(((pw >> 8) & 0xFFu) == 0u);
        const int f = (__popcll(m3) >= 56) ? ((__popcll(m1) >= 56) ? 2 : 1) : 0;

        const size_t idx = (size_t)(blockIdx.x - QXB) * 256 + tid;
        const size_t off = idx * 8;

        unsigned lo, hi;
        if (f == 2) {              // float32 upcast delivery (values exactly on fp8 grid)
            const float4* p = (const float4*)((const float*)wq + off);
            const float4 a = p[0], b = p[1];
            lo = e4m3_encode(a.x) | (e4m3_encode(a.y) << 8) | (e4m3_encode(a.z) << 16) | (e4m3_encode(a.w) << 24);
            hi = e4m3_encode(b.x) | (e4m3_encode(b.y) << 8) | (e4m3_encode(b.z) << 16) | (e4m3_encode(b.w) << 24);
        } else if (f == 1) {       // bf16 upcast delivery
            const ushort4 h0 = *(const ushort4*)((const unsigned short*)wq + off);
            const ushort4 h1 = *(((const ushort4*)((const unsigned short*)wq + off)) + 1);
            lo = e4m3_encode(__uint_as_float((unsigned)h0.x << 16))
               | (e4m3_encode(__uint_as_float((unsigned)h0.y << 16)) << 8)
               | (e4m3_encode(__uint_as_float((unsigned)h0.z << 16)) << 16)
               | (e4m3_encode(__uint_as_float((unsigned)h0.w << 16)) << 24);
            hi = e4m3_encode(__uint_as_float((unsigned)h1.x << 16))
               | (e4m3_encode(__uint_as_float((unsigned)h1.y << 16)) << 8)
               | (e4m3_encode(__uint_as_float((unsigned)h1.z << 16)) << 16)
               | (e4m3_encode(__uint_as_float((unsigned)h1.w << 16)) << 24);
        } else {                   // already raw fp8 bytes
            const uint2 d = *(const uint2*)((const unsigned char*)wq + off);
            lo = d.x; hi = d.y;
        }
        *(uint2*)(wq8 + off) = make_uint2(lo, hi);
    }
}

// ---------------------------------------------------------------------------
// Primary GEMM: EXACTLY the round-6 schedule (54.4 µs measured: 128x128 tile,
// 4 waves 2x2 of 64x64, MX fp8 K=128, single-buffer 2-barrier loop,
// XOR-swizzled 16B chunks, 128-total-reg occupancy shape: bf[4] held inside
// the tile only, af rolling, premultiplied sxs, launch_bounds(256,4)) plus
// the two independently-verified deltas from round 7, UNBUNDLED from the
// spilling split-stage:
//   1. XCD-grouped bijective tile map (1024 blocks): XCD g owns m-tiles
//      [8g,8g+8) x all 16 n-tiles (R7 measured FETCH 73->61.5 MB). Shorter
//      effective stage latency lands directly in the exposed issue->drain
//      gap, which is the critical path of this schedule.
//   2. Serial-pointer STAGE: one rolling temp pointer per stage instead of
//      4 materialized 64-bit addresses -> lower VGPR pressure in the loop.
// NO fragment is live across any barrier (the R7 spill mechanism).
// Spill tripwire: WRITE_SIZE must stay ~70e3 KB (R7's 125e3 = scratch).
// ---------------------------------------------------------------------------
__global__ __launch_bounds__(256, 4) void gemm_mx_kernel(const unsigned char* __restrict__ Aq,
                                                         const unsigned char* __restrict__ Bq,
                                                         const float* __restrict__ xs,
                                                         const float* __restrict__ wsc,
                                                         float* __restrict__ C) {
    __shared__ unsigned char sA[128 * 128];   // 16 KB
    __shared__ unsigned char sB[128 * 128];   // 16 KB
    __shared__ float sxs[KB][128];            // 8 KB combined scales xs*wsk

    const int tid  = threadIdx.x;
    const int wave = tid >> 6;
    const int lane = tid & 63;
    const int lrow = lane & 15;
    const int lk   = lane >> 4;          // k-group (32 bytes each)
    const int lk4  = lk * 4;
    const int wm   = (wave & 1) * 64;
    const int wn   = (wave >> 1) * 64;

    // XCD-grouped bijective tile map: 1024 blocks (64 m-tiles x 16 n-tiles);
    // XCD g (bid&7==g) owns lid in [128g,128g+128) = m-tiles [8g,8g+8).
    const int bid = blockIdx.x;
    const int lid = ((bid & 7) << 7) | (bid >> 3);
    const int m0  = (lid >> 4) * 128;
    const int n0  = (lid & 15) * 128;
    const int nb  = n0 >> 7;

    // staging: thread t -> LDS bytes [t*16 + it*4096): row = t/8 + it*32,
    // physical chunk = t&7 holding logical chunk (t&7)^(row&7).
    const int srow = tid >> 3;
    const int gck  = (tid & 7) ^ (srow & 7);
    const unsigned char* agp = Aq + (size_t)(m0 + srow) * KDIM + gck * 16;
    const unsigned char* bgp = Bq + (size_t)(n0 + srow) * KDIM + gck * 16;

    // serial-pointer stages: one rolling temp, 16-B LDS-linear dests
#define STAGE_A(kb_) do {                                                             \
    const unsigned char* _p = agp + (size_t)(kb_) * QBLK;                             \
    __builtin_amdgcn_global_load_lds((const AS1 void*)_p, (AS3 void*)(sA + tid * 16),            16, 0, 0); \
    _p += (size_t)32 * KDIM;                                                          \
    __builtin_amdgcn_global_load_lds((const AS1 void*)_p, (AS3 void*)(sA + tid * 16 + 4096),     16, 0, 0); \
    _p += (size_t)32 * KDIM;                                                          \
    __builtin_amdgcn_global_load_lds((const AS1 void*)_p, (AS3 void*)(sA + tid * 16 + 8192),     16, 0, 0); \
    _p += (size_t)32 * KDIM;                                                          \
    __builtin_amdgcn_global_load_lds((const AS1 void*)_p, (AS3 void*)(sA + tid * 16 + 12288),    16, 0, 0); \
} while (0)
#define STAGE_B(kb_) do {                                                             \
    const unsigned char* _p = bgp + (size_t)(kb_) * QBLK;                             \
    __builtin_amdgcn_global_load_lds((const AS1 void*)_p, (AS3 void*)(sB + tid * 16),            16, 0, 0); \
    _p += (size_t)32 * KDIM;                                                          \
    __builtin_amdgcn_global_load_lds((const AS1 void*)_p, (AS3 void*)(sB + tid * 16 + 4096),     16, 0, 0); \
    _p += (size_t)32 * KDIM;                                                          \
    __builtin_amdgcn_global_load_lds((const AS1 void*)_p, (AS3 void*)(sB + tid * 16 + 8192),     16, 0, 0); \
    _p += (size_t)32 * KDIM;                                                          \
    __builtin_amdgcn_global_load_lds((const AS1 void*)_p, (AS3 void*)(sB + tid * 16 + 12288),    16, 0, 0); \
} while (0)

    // one-time combined-scale staging (ordered by the loop's first barrier)
    if (tid < 128) {
        const float4* xp = (const float4*)(xs + (size_t)(m0 + tid) * KB);
        const float* wp = wsc + nb * KB;
#pragma unroll
        for (int q = 0; q < 4; ++q) {
            const float4 v = xp[q];
            sxs[q * 4 + 0][tid] = v.x * wp[q * 4 + 0];
            sxs[q * 4 + 1][tid] = v.y * wp[q * 4 + 1];
            sxs[q * 4 + 2][tid] = v.z * wp[q * 4 + 2];
            sxs[q * 4 + 3][tid] = v.w * wp[q * 4 + 3];
        }
    }

    floatx4 acc[4][4] = {};
    const floatx4 zero = {0.f, 0.f, 0.f, 0.f};

    for (int kb = 0; kb < KB; ++kb) {            // 16 iterations, 128 K each
        __syncthreads();                         // everyone done with t-1 tiles
        STAGE_A(kb);
        STAGE_B(kb);
        __syncthreads();                         // vmcnt(0): tile landed

        // B fragments held (32 regs); A fragment read per-i (8 regs live)
        int8v bf[4];
#pragma unroll
        for (int j = 0; j < 4; ++j) {
            const int Rb = wn + j * 16 + lrow;
            const int d0 = (lk * 2) ^ (Rb & 7);
            const int d1 = (lk * 2 + 1) ^ (Rb & 7);
            int4v blo = *(const int4v*)(sB + Rb * 128 + d0 * 16);
            int4v bhi = *(const int4v*)(sB + Rb * 128 + d1 * 16);
            bf[j] = __builtin_shufflevector(blo, bhi, 0, 1, 2, 3, 4, 5, 6, 7);
        }

#pragma unroll
        for (int i = 0; i < 4; ++i) {
            const int Ra = wm + i * 16 + lrow;
            const int c0 = (lk * 2) ^ (Ra & 7);
            const int c1 = (lk * 2 + 1) ^ (Ra & 7);
            int4v alo = *(const int4v*)(sA + Ra * 128 + c0 * 16);
            int4v ahi = *(const int4v*)(sA + Ra * 128 + c1 * 16);
            int8v af = __builtin_shufflevector(alo, ahi, 0, 1, 2, 3, 4, 5, 6, 7);

            // combined per-row scales for this k-block (C/D row = lk*4 + r)
            const floatx4 cs = *(const floatx4*)&sxs[kb][wm + i * 16 + lk4];

#pragma unroll
            for (int j = 0; j < 4; ++j) {
                floatx4 blk = __builtin_amdgcn_mfma_scale_f32_16x16x128_f8f6f4(
                    af, bf[j], zero, 0, 0, 0, 0x7F7F7F7F, 0, 0x7F7F7F7F);
#pragma unroll
                for (int r = 0; r < 4; ++r)
                    acc[i][j][r] += cs[r] * blk[r];
            }
        }
    }
#undef STAGE_A
#undef STAGE_B

    // Epilogue: col = lane&15, row = lk*4 + r.
#pragma unroll
    for (int i = 0; i < 4; ++i) {
        const int row0 = m0 + wm + i * 16 + lk4;
#pragma unroll
        for (int r = 0; r < 4; ++r) {
            float* cp = C + (size_t)(row0 + r) * NDIM + n0 + wn + lrow;
#pragma unroll
            for (int j = 0; j < 4; ++j)
                cp[j * 16] = acc[i][j][r];
        }
    }
}

// ---------------------------------------------------------------------------
extern "C" void kernel_launch(void* const* d_in, const int* in_sizes, int n_in,
                              void* d_out, int out_size, void* d_ws, size_t ws_size,
                              hipStream_t stream) {
    const float* x      = (const float*)d_in[0];
    const void* wq      = d_in[1];
    const float* wscale = (const float*)d_in[2];
    float* y            = (float*)d_out;

    unsigned char* xq  = (unsigned char*)d_ws + XQ_OFF;
    unsigned char* wq8 = (unsigned char*)d_ws + WQ_OFF;
    float* xs          = (float*)((unsigned char*)d_ws + XS_OFF);

    prep_kernel<<<QXB + DWB, 256, 0, stream>>>(x, wq, xq, wq8, xs);
    gemm_mx_kernel<<<(MDIM / 128) * (NDIM / 128), 256, 0, stream>>>(xq, wq8, xs, wscale, y);
}